// Round 1
// baseline (9101.221 us; speedup 1.0000x reference)
//
#include <hip/hip_runtime.h>
#include <hip/hip_bf16.h>

#define TT 256
#define BB 128
#define EMBD 256
#define HID 512
#define KTAG 12
#define START_TAG 10
#define STOP_TAG 11
#define KTOT 768   // EMBD + HID
#define KC 64
#define KCP 68     // padded LDS row (floats); 68*4B keeps 16B alignment, breaks bank conflicts

__device__ __forceinline__ float sigm(float x) { return 1.0f / (1.0f + expf(-x)); }

// ---------------- init: state copy + bias sums ----------------
__global__ void init_kernel(const float* __restrict__ h0, const float* __restrict__ c0,
                            const float* __restrict__ bihf, const float* __restrict__ bhhf,
                            const float* __restrict__ bihb, const float* __restrict__ bhhb,
                            float* __restrict__ h_f0, float* __restrict__ h_b0,
                            float* __restrict__ c_f, float* __restrict__ c_b,
                            float* __restrict__ bias_f, float* __restrict__ bias_b)
{
    int i = blockIdx.x * blockDim.x + threadIdx.x;
    const int n = BB * HID;
    if (i < n) {
        h_f0[i] = h0[i];
        h_b0[i] = h0[n + i];
        c_f[i]  = c0[i];
        c_b[i]  = c0[n + i];
    }
    if (i < 4 * HID) {
        bias_f[i] = bihf[i] + bhhf[i];
        bias_b[i] = bihb[i] + bhhb[i];
    }
}

// ---------------- one LSTM timestep (fwd t=s, bwd t=TT-1-s fused) ----------------
// grid: 256 blocks = dir(2) x btile(4 of 32 rows) x utile(32 of 16 units)
// each block computes gates[32 b][16 u][4 gates] and does the pointwise update inline.
__launch_bounds__(256, 1)
__global__ void lstm_step_kernel(const int* __restrict__ x, const int* __restrict__ lengths,
    const float* __restrict__ embedding,
    const float* __restrict__ Wih_f, const float* __restrict__ Whh_f,
    const float* __restrict__ Wih_b, const float* __restrict__ Whh_b,
    const float* __restrict__ bias_f, const float* __restrict__ bias_b,
    const float* __restrict__ hf_in, float* __restrict__ hf_out, float* __restrict__ cf,
    const float* __restrict__ hb_in, float* __restrict__ hb_out, float* __restrict__ cb,
    __hip_bfloat16* __restrict__ hsf, __hip_bfloat16* __restrict__ hsb, int s)
{
    __shared__ float As[32][KCP];
    __shared__ float Bs[64][KCP];
    __shared__ int   xi[32];

    int blk   = blockIdx.x;
    int dir   = blk & 1;
    int btile = (blk >> 1) & 3;
    int utile = blk >> 3;          // 0..31
    int b0 = btile * 32;
    int u0 = utile * 16;
    int t  = dir ? (TT - 1 - s) : s;

    const float* Wih  = dir ? Wih_b  : Wih_f;
    const float* Whh  = dir ? Whh_b  : Whh_f;
    const float* bias = dir ? bias_b : bias_f;
    const float* h_in = dir ? hb_in  : hf_in;
    float* h_out      = dir ? hb_out : hf_out;
    float* c_st       = dir ? cb     : cf;
    __hip_bfloat16* hs = dir ? hsb   : hsf;

    int tid = threadIdx.x;
    if (tid < 32) xi[tid] = x[(b0 + tid) * TT + t];
    __syncthreads();

    int tx = tid & 15;    // u within tile
    int ty = tid >> 4;    // pair of b rows
    float acc[2][4] = {{0.f,0.f,0.f,0.f},{0.f,0.f,0.f,0.f}};

    for (int k0 = 0; k0 < KTOT; k0 += KC) {
        // stage A: 32 rows x 64 k  (emb row for k<256, h for k>=256)
        #pragma unroll
        for (int w = 0; w < 2; w++) {
            int slot = tid + w * 256;
            int bl = slot >> 4;
            int kq = (slot & 15) * 4;
            int kg = k0 + kq;
            float4 v;
            if (kg < EMBD) v = *(const float4*)(embedding + (size_t)xi[bl] * EMBD + kg);
            else           v = *(const float4*)(h_in + (size_t)(b0 + bl) * HID + (kg - EMBD));
            *(float4*)&As[bl][kq] = v;
        }
        // stage B: 64 rows (16 u x 4 gates) x 64 k
        #pragma unroll
        for (int w = 0; w < 4; w++) {
            int slot = tid + w * 256;
            int jl = slot >> 4;
            int kq = (slot & 15) * 4;
            int g = jl >> 4, uu = jl & 15;
            int row = g * HID + u0 + uu;
            int kg = k0 + kq;
            float4 v;
            if (kg < EMBD) v = *(const float4*)(Wih + (size_t)row * EMBD + kg);
            else           v = *(const float4*)(Whh + (size_t)row * HID + (kg - EMBD));
            *(float4*)&Bs[jl][kq] = v;
        }
        __syncthreads();
        #pragma unroll
        for (int kk = 0; kk < KC; kk += 4) {
            float4 a0 = *(const float4*)&As[ty * 2 + 0][kk];
            float4 a1 = *(const float4*)&As[ty * 2 + 1][kk];
            #pragma unroll
            for (int g = 0; g < 4; g++) {
                float4 bv = *(const float4*)&Bs[g * 16 + tx][kk];
                acc[0][g] += a0.x*bv.x + a0.y*bv.y + a0.z*bv.z + a0.w*bv.w;
                acc[1][g] += a1.x*bv.x + a1.y*bv.y + a1.z*bv.z + a1.w*bv.w;
            }
        }
        __syncthreads();
    }

    // pointwise LSTM update: gate order i,f,g,o ; masked steps carry state
    int u = u0 + tx;
    #pragma unroll
    for (int bi = 0; bi < 2; bi++) {
        int b = b0 + ty * 2 + bi;
        float gi = acc[bi][0] + bias[0 * HID + u];
        float gf = acc[bi][1] + bias[1 * HID + u];
        float gg = acc[bi][2] + bias[2 * HID + u];
        float go = acc[bi][3] + bias[3 * HID + u];
        int idx = b * HID + u;
        float c_old = c_st[idx];
        float h_old = h_in[idx];
        float cn = sigm(gf) * c_old + sigm(gi) * tanhf(gg);
        float hn = sigm(go) * tanhf(cn);
        bool msk = (t < lengths[b]);
        float c_new = msk ? cn : c_old;
        float h_new = msk ? hn : h_old;
        c_st[idx]  = c_new;
        h_out[idx] = h_new;
        hs[((size_t)t * BB + b) * HID + u] = __float2bfloat16(h_new);
    }
}

// ---------------- emissions: [T*B,12] = concat(hs_f,hs_b) @ fc_W^T + fc_b ----------------
__global__ void emissions_kernel(const __hip_bfloat16* __restrict__ hsf,
                                 const __hip_bfloat16* __restrict__ hsb,
                                 const float* __restrict__ fcW, const float* __restrict__ fcb,
                                 float* __restrict__ emis)
{
    int idx = blockIdx.x * blockDim.x + threadIdx.x;   // t*BB + b
    if (idx >= TT * BB) return;
    float acc[KTAG];
    #pragma unroll
    for (int k = 0; k < KTAG; k++) acc[k] = fcb[k];
    const __hip_bfloat16* hf = hsf + (size_t)idx * HID;
    const __hip_bfloat16* hb = hsb + (size_t)idx * HID;
    for (int kk = 0; kk < HID; kk++) {
        float hv = __bfloat162float(hf[kk]);
        #pragma unroll
        for (int k = 0; k < KTAG; k++) acc[k] += hv * fcW[k * (2 * HID) + kk];
    }
    for (int kk = 0; kk < HID; kk++) {
        float hv = __bfloat162float(hb[kk]);
        #pragma unroll
        for (int k = 0; k < KTAG; k++) acc[k] += hv * fcW[k * (2 * HID) + HID + kk];
    }
    float* e = emis + (size_t)idx * KTAG;
    #pragma unroll
    for (int k = 0; k < KTAG; k++) e[k] = acc[k];
}

// ---------------- CRF log-partition: one wave per batch row ----------------
__global__ void crf_partition_kernel(const float* __restrict__ emis, const int* __restrict__ lengths,
                                     const float* __restrict__ trans, float* __restrict__ logz)
{
    int b = blockIdx.x;
    int lane = threadIdx.x;   // blockDim = 64 (one wave)
    float trow[KTAG];
    #pragma unroll
    for (int j = 0; j < KTAG; j++)
        trow[j] = (lane < KTAG) ? trans[lane * KTAG + j] : -1e30f;
    float alpha = (lane == START_TAG) ? 0.0f : -10000.0f;
    int len = lengths[b];
    for (int t = 0; t < len; t++) {     // mask t<len is monotone -> frozen after len
        float sc[KTAG];
        #pragma unroll
        for (int j = 0; j < KTAG; j++) {
            float aj = __shfl(alpha, j, 64);
            sc[j] = aj + trow[j];
        }
        float m = sc[0];
        #pragma unroll
        for (int j = 1; j < KTAG; j++) m = fmaxf(m, sc[j]);
        float ssum = 0.0f;
        #pragma unroll
        for (int j = 0; j < KTAG; j++) ssum += expf(sc[j] - m);
        float em = (lane < KTAG) ? emis[((size_t)t * BB + b) * KTAG + lane] : 0.0f;
        float anew = m + logf(ssum) + em;
        alpha = (lane < KTAG) ? anew : alpha;
    }
    float v = (lane < KTAG) ? (alpha + trans[STOP_TAG * KTAG + lane]) : -1e30f;
    float m = v;
    #pragma unroll
    for (int off = 1; off < 16; off <<= 1) m = fmaxf(m, __shfl_xor(m, off, 64));
    float e = expf(v - m);
    #pragma unroll
    for (int off = 1; off < 16; off <<= 1) e += __shfl_xor(e, off, 64);
    if (lane == 0) logz[b] = m + logf(e);
}

// ---------------- gold score + final output ----------------
__global__ void gold_kernel(const float* __restrict__ emis, const int* __restrict__ tags,
                            const int* __restrict__ lengths, const float* __restrict__ trans,
                            const float* __restrict__ logz, float* __restrict__ out)
{
    int b = blockIdx.x * blockDim.x + threadIdx.x;
    if (b >= BB) return;
    int len = lengths[b];
    float score = 0.0f;
    int prev = START_TAG;
    for (int t = 0; t < len; t++) {
        int nxt = tags[b * TT + t];
        score += trans[nxt * KTAG + prev] + emis[((size_t)t * BB + b) * KTAG + nxt];
        prev = nxt;
    }
    score += trans[STOP_TAG * KTAG + prev];
    out[b] = logz[b] - score;
}

extern "C" void kernel_launch(void* const* d_in, const int* in_sizes, int n_in,
                              void* d_out, int out_size, void* d_ws, size_t ws_size,
                              hipStream_t stream)
{
    (void)in_sizes; (void)n_in; (void)out_size; (void)ws_size;
    const int*   x     = (const int*)d_in[0];
    const int*   lens  = (const int*)d_in[1];
    const int*   tags  = (const int*)d_in[2];
    const float* emb   = (const float*)d_in[3];
    const float* Wihf  = (const float*)d_in[4];
    const float* Whhf  = (const float*)d_in[5];
    const float* bihf  = (const float*)d_in[6];
    const float* bhhf  = (const float*)d_in[7];
    const float* Wihb  = (const float*)d_in[8];
    const float* Whhb  = (const float*)d_in[9];
    const float* bihb  = (const float*)d_in[10];
    const float* bhhb  = (const float*)d_in[11];
    const float* fcW   = (const float*)d_in[12];
    const float* fcb   = (const float*)d_in[13];
    const float* trans = (const float*)d_in[14];
    const float* h0    = (const float*)d_in[15];
    const float* c0    = (const float*)d_in[16];
    float* out = (float*)d_out;

    char* ws = (char*)d_ws;
    size_t off = 0;
    auto alloc = [&](size_t bytes) {
        void* p = ws + off;
        off += (bytes + 255) & ~(size_t)255;
        return p;
    };
    __hip_bfloat16* hsf = (__hip_bfloat16*)alloc((size_t)TT * BB * HID * 2);
    __hip_bfloat16* hsb = (__hip_bfloat16*)alloc((size_t)TT * BB * HID * 2);
    float* emis  = (float*)alloc((size_t)TT * BB * KTAG * 4);
    float* hf0   = (float*)alloc((size_t)BB * HID * 4);
    float* hf1   = (float*)alloc((size_t)BB * HID * 4);
    float* hb0   = (float*)alloc((size_t)BB * HID * 4);
    float* hb1   = (float*)alloc((size_t)BB * HID * 4);
    float* cf    = (float*)alloc((size_t)BB * HID * 4);
    float* cb    = (float*)alloc((size_t)BB * HID * 4);
    float* biasf = (float*)alloc((size_t)4 * HID * 4);
    float* biasb = (float*)alloc((size_t)4 * HID * 4);
    float* logz  = (float*)alloc((size_t)BB * 4);
    float* hfb[2] = { hf0, hf1 };
    float* hbb[2] = { hb0, hb1 };

    init_kernel<<<256, 256, 0, stream>>>(h0, c0, bihf, bhhf, bihb, bhhb,
                                         hfb[0], hbb[0], cf, cb, biasf, biasb);
    for (int s = 0; s < TT; s++) {
        int cur = s & 1, nxt = cur ^ 1;
        lstm_step_kernel<<<256, 256, 0, stream>>>(x, lens, emb, Wihf, Whhf, Wihb, Whhb,
            biasf, biasb, hfb[cur], hfb[nxt], cf, hbb[cur], hbb[nxt], cb, hsf, hsb, s);
    }
    emissions_kernel<<<(TT * BB + 255) / 256, 256, 0, stream>>>(hsf, hsb, fcW, fcb, emis);
    crf_partition_kernel<<<BB, 64, 0, stream>>>(emis, lens, trans, logz);
    gold_kernel<<<1, BB, 0, stream>>>(emis, tags, lens, trans, logz, out);
}

// Round 2
// 3284.882 us; speedup vs baseline: 2.7706x; 2.7706x over previous
//
#include <hip/hip_runtime.h>
#include <hip/hip_bf16.h>

#define TT 256
#define BB 128
#define EMBD 256
#define HID 512
#define KTAG 12
#define START_TAG 10
#define STOP_TAG 11

typedef __attribute__((ext_vector_type(8))) short short8;
typedef __attribute__((ext_vector_type(4))) float f32x4;

__device__ __forceinline__ float sigm(float x) { return 1.0f / (1.0f + expf(-x)); }

__device__ __forceinline__ unsigned short f2bf(float f) {
    union { float f; unsigned int u; } v; v.f = f;
    unsigned int r = v.u + 0x7fffu + ((v.u >> 16) & 1u);   // RNE (inputs are tame, no NaN/Inf)
    return (unsigned short)(r >> 16);
}

__device__ __forceinline__ void gll16(const void* g, void* l) {
    __builtin_amdgcn_global_load_lds((const __attribute__((address_space(1))) void*)g,
                                     (__attribute__((address_space(3))) void*)l, 16, 0, 0);
}

// ---------------- prologue: state init (bf16 h, f32 c) + bias sums ----------------
__global__ void prep_state(const float* __restrict__ h0, const float* __restrict__ c0,
                           const float* __restrict__ bihf, const float* __restrict__ bhhf,
                           const float* __restrict__ bihb, const float* __restrict__ bhhb,
                           unsigned short* __restrict__ hbuf, float* __restrict__ cbuf,
                           float* __restrict__ bias2)
{
    int i = blockIdx.x * blockDim.x + threadIdx.x;
    const int n2 = 2 * BB * HID;
    if (i < n2) {
        hbuf[i] = f2bf(h0[i]);
        cbuf[i] = c0[i];
    }
    if (i < 2 * 2048) {
        int dir = i >> 11, j = i & 2047;
        bias2[i] = dir ? (bihb[j] + bhhb[j]) : (bihf[j] + bhhf[j]);
    }
}

// ---------------- prologue: gather embeddings -> bf16 xs[T][B][EMBD] ----------------
__global__ void xs_gather(const int* __restrict__ x, const float* __restrict__ emb,
                          unsigned short* __restrict__ xs)
{
    int i = blockIdx.x * blockDim.x + threadIdx.x;   // one 8-elem chunk each
    if (i >= TT * BB * (EMBD / 8)) return;
    int chk = i & 31;            // EMBD/8 = 32
    int row = i >> 5;            // t*BB + b
    int b = row & (BB - 1);
    int t = row >> 7;
    const float* src = emb + (size_t)x[b * TT + t] * EMBD + chk * 8;
    float4 v0 = *(const float4*)(src);
    float4 v1 = *(const float4*)(src + 4);
    unsigned short tmp[8];
    tmp[0] = f2bf(v0.x); tmp[1] = f2bf(v0.y); tmp[2] = f2bf(v0.z); tmp[3] = f2bf(v0.w);
    tmp[4] = f2bf(v1.x); tmp[5] = f2bf(v1.y); tmp[6] = f2bf(v1.z); tmp[7] = f2bf(v1.w);
    *(uint4*)(xs + (size_t)row * EMBD + chk * 8) = *(const uint4*)tmp;
}

// ---------------- prologue: reorder + concat weights -> bf16 Wr[2][2048][768] ----------------
// new row nr = utile*32 + g*8 + uu  (u = utile*8+uu), cols = [Wih row | Whh row]
__global__ void w_reorder(const float* __restrict__ Wihf, const float* __restrict__ Whhf,
                          const float* __restrict__ Wihb, const float* __restrict__ Whhb,
                          unsigned short* __restrict__ Wr)
{
    int i = blockIdx.x * blockDim.x + threadIdx.x;   // one 8-elem chunk each
    if (i >= 2 * 2048 * (768 / 8)) return;
    int c8 = i % 96;
    int r2 = i / 96;
    int nr = r2 & 2047;
    int dir = r2 >> 11;
    int utile = nr >> 5;
    int g = (nr >> 3) & 3;
    int uu = nr & 7;
    int orow = g * HID + utile * 8 + uu;
    int k0 = c8 * 8;
    const float* Wih = dir ? Wihb : Wihf;
    const float* Whh = dir ? Whhb : Whhf;
    const float* src = (k0 < EMBD) ? (Wih + (size_t)orow * EMBD + k0)
                                   : (Whh + (size_t)orow * HID + (k0 - EMBD));
    float4 v0 = *(const float4*)(src);
    float4 v1 = *(const float4*)(src + 4);
    unsigned short tmp[8];
    tmp[0] = f2bf(v0.x); tmp[1] = f2bf(v0.y); tmp[2] = f2bf(v0.z); tmp[3] = f2bf(v0.w);
    tmp[4] = f2bf(v1.x); tmp[5] = f2bf(v1.y); tmp[6] = f2bf(v1.z); tmp[7] = f2bf(v1.w);
    *(uint4*)(Wr + ((size_t)dir * 2048 + nr) * 768 + k0) = *(const uint4*)tmp;
}

// ---------------- one LSTM timestep, MFMA (fwd t=s, bwd t=TT-1-s fused) ----------------
// grid 256 = dir(2) x btile(2 of 64 rows) x utile(64 of 8 units); 256 threads = 4 waves.
// Block output tile: 64 batch x 32 gate-rows (4 gates x 8 units), K = 768 (emb 256 | h 512).
// LDS in fragment order: subtile(16rows x 32k) = 1KB at subtile*1024 + lane*16.
__launch_bounds__(256, 1)
__global__ void lstm_step_mfma(
    const unsigned short* __restrict__ xs, const unsigned short* __restrict__ Wr,
    const float* __restrict__ bias2, const int* __restrict__ lengths,
    const unsigned short* __restrict__ h_in, unsigned short* __restrict__ h_out,
    float* __restrict__ c_st,
    unsigned short* __restrict__ hsf, unsigned short* __restrict__ hsb, int s)
{
    __shared__ __align__(16) unsigned short Abuf[2][8 * 512];   // 8 subtiles (4 mt x 2 ks)
    __shared__ __align__(16) unsigned short Bbuf[2][4 * 512];   // 4 subtiles (2 nt x 2 ks)
    __shared__ float gl[64][33];

    const int blk = blockIdx.x;
    const int dir = blk >> 7;
    const int btile = (blk >> 6) & 1;
    const int utile = blk & 63;
    const int t = dir ? (TT - 1 - s) : s;

    const int tid = threadIdx.x;
    const int w = tid >> 6;
    const int l = tid & 63;
    const int l15 = l & 15;
    const int l16 = l >> 4;
    const int bg0 = btile * 64;

    const unsigned short* hsrc = h_in + (size_t)dir * BB * HID;
    const unsigned short* Wb = Wr + ((size_t)dir * 2048 + utile * 32) * 768;

    f32x4 acc0 = {0.f, 0.f, 0.f, 0.f}, acc1 = {0.f, 0.f, 0.f, 0.f};

    const int arow = w * 16 + l15;          // this wave's A row (local 0..63)

    auto stage = [&](int kc, int bi) {
        #pragma unroll
        for (int q = 0; q < 2; q++) {
            int cq = q * 4 + l16;           // 16B chunk col 0..7
            int kg = kc * 64 + cq * 8;
            const unsigned short* src;
            if (kc < 4) src = xs + ((size_t)t * BB + (bg0 + arow)) * EMBD + kg;
            else        src = hsrc + (size_t)(bg0 + arow) * HID + (kg - EMBD);
            gll16(src, &Abuf[bi][(2 * w + q) * 512]);       // dest wave-uniform; +lane*16 by HW
        }
        {
            int cq = (w & 1) * 4 + l16;
            int nrow = (w >> 1) * 16 + l15;
            const unsigned short* src = Wb + (size_t)nrow * 768 + kc * 64 + cq * 8;
            gll16(src, &Bbuf[bi][w * 512]);
        }
    };

    auto compute = [&](int bi) {
        #pragma unroll
        for (int ks = 0; ks < 2; ks++) {
            short8 a  = *(const short8*)&Abuf[bi][(2 * w + ks) * 512 + l * 8];
            short8 b0 = *(const short8*)&Bbuf[bi][(ks) * 512 + l * 8];
            short8 b1 = *(const short8*)&Bbuf[bi][(2 + ks) * 512 + l * 8];
            acc0 = __builtin_amdgcn_mfma_f32_16x16x32_bf16(a, b0, acc0, 0, 0, 0);
            acc1 = __builtin_amdgcn_mfma_f32_16x16x32_bf16(a, b1, acc1, 0, 0, 0);
        }
    };

    stage(0, 0);
    __syncthreads();
    for (int kc = 0; kc < 12; kc++) {
        int bi = kc & 1;
        if (kc < 11) stage(kc + 1, bi ^ 1);
        compute(bi);
        __syncthreads();
    }

    // accumulators -> gate LDS  (C layout: col = l&15, row = 4*(l>>4)+r)
    {
        int bb = w * 16 + l16 * 4;
        #pragma unroll
        for (int r = 0; r < 4; r++) {
            gl[bb + r][l15]      = acc0[r];
            gl[bb + r][16 + l15] = acc1[r];
        }
    }
    __syncthreads();

    const float* bias = bias2 + dir * 2048;
    unsigned short* hs = dir ? hsb : hsf;
    #pragma unroll
    for (int pp = 0; pp < 2; pp++) {
        int p = pp * 256 + tid;            // 512 (b,uu) pairs
        int bl = p >> 3, uu = p & 7;
        int bgl = bg0 + bl;
        int u = utile * 8 + uu;
        float gi = gl[bl][uu]      + bias[u];
        float gf = gl[bl][8 + uu]  + bias[512 + u];
        float gg = gl[bl][16 + uu] + bias[1024 + u];
        float go = gl[bl][24 + uu] + bias[1536 + u];
        size_t idx = ((size_t)dir * BB + bgl) * HID + u;
        float c_old = c_st[idx];
        float cn = sigm(gf) * c_old + sigm(gi) * tanhf(gg);
        float hn = sigm(go) * tanhf(cn);
        bool msk = t < lengths[bgl];
        unsigned short hv;
        if (msk) { c_st[idx] = cn; hv = f2bf(hn); }
        else     { hv = h_in[idx]; }
        h_out[idx] = hv;
        hs[((size_t)t * BB + bgl) * HID + u] = hv;
    }
}

// ---------------- emissions: one wave per (t,b) row ----------------
__global__ void emissions_wave(const unsigned short* __restrict__ hsf,
                               const unsigned short* __restrict__ hsb,
                               const float* __restrict__ fcW, const float* __restrict__ fcb,
                               float* __restrict__ emis)
{
    int wid = (blockIdx.x * blockDim.x + threadIdx.x) >> 6;
    int l = threadIdx.x & 63;
    if (wid >= TT * BB) return;
    uint4 vf = *(const uint4*)(hsf + (size_t)wid * HID + l * 8);
    uint4 vb = *(const uint4*)(hsb + (size_t)wid * HID + l * 8);
    unsigned int uf[4] = {vf.x, vf.y, vf.z, vf.w};
    unsigned int ub[4] = {vb.x, vb.y, vb.z, vb.w};
    float xf[8], xb[8];
    #pragma unroll
    for (int j = 0; j < 4; j++) {
        xf[2*j]   = __uint_as_float(uf[j] << 16);
        xf[2*j+1] = __uint_as_float(uf[j] & 0xffff0000u);
        xb[2*j]   = __uint_as_float(ub[j] << 16);
        xb[2*j+1] = __uint_as_float(ub[j] & 0xffff0000u);
    }
    float acc[KTAG];
    #pragma unroll
    for (int k = 0; k < KTAG; k++) {
        const float* wfp = fcW + k * 1024 + l * 8;
        const float* wbp = fcW + k * 1024 + 512 + l * 8;
        float a = 0.f;
        #pragma unroll
        for (int j = 0; j < 8; j++) a += xf[j] * wfp[j] + xb[j] * wbp[j];
        acc[k] = a;
    }
    #pragma unroll
    for (int k = 0; k < KTAG; k++) {
        #pragma unroll
        for (int off = 32; off >= 1; off >>= 1) acc[k] += __shfl_xor(acc[k], off, 64);
    }
    if (l == 0) {
        float* e = emis + (size_t)wid * KTAG;
        #pragma unroll
        for (int k = 0; k < KTAG; k++) e[k] = acc[k] + fcb[k];
    }
}

// ---------------- CRF log-partition: one wave per batch row ----------------
__global__ void crf_partition_kernel(const float* __restrict__ emis, const int* __restrict__ lengths,
                                     const float* __restrict__ trans, float* __restrict__ logz)
{
    int b = blockIdx.x;
    int lane = threadIdx.x;   // blockDim = 64
    float trow[KTAG];
    #pragma unroll
    for (int j = 0; j < KTAG; j++)
        trow[j] = (lane < KTAG) ? trans[lane * KTAG + j] : -1e30f;
    float alpha = (lane == START_TAG) ? 0.0f : -10000.0f;
    int len = lengths[b];
    for (int t = 0; t < len; t++) {
        float sc[KTAG];
        #pragma unroll
        for (int j = 0; j < KTAG; j++) {
            float aj = __shfl(alpha, j, 64);
            sc[j] = aj + trow[j];
        }
        float m = sc[0];
        #pragma unroll
        for (int j = 1; j < KTAG; j++) m = fmaxf(m, sc[j]);
        float ssum = 0.0f;
        #pragma unroll
        for (int j = 0; j < KTAG; j++) ssum += expf(sc[j] - m);
        float em = (lane < KTAG) ? emis[((size_t)t * BB + b) * KTAG + lane] : 0.0f;
        float anew = m + logf(ssum) + em;
        alpha = (lane < KTAG) ? anew : alpha;
    }
    float v = (lane < KTAG) ? (alpha + trans[STOP_TAG * KTAG + lane]) : -1e30f;
    float m = v;
    #pragma unroll
    for (int off = 1; off < 16; off <<= 1) m = fmaxf(m, __shfl_xor(m, off, 64));
    float e = expf(v - m);
    #pragma unroll
    for (int off = 1; off < 16; off <<= 1) e += __shfl_xor(e, off, 64);
    if (lane == 0) logz[b] = m + logf(e);
}

// ---------------- gold score + final output ----------------
__global__ void gold_kernel(const float* __restrict__ emis, const int* __restrict__ tags,
                            const int* __restrict__ lengths, const float* __restrict__ trans,
                            const float* __restrict__ logz, float* __restrict__ out)
{
    int b = blockIdx.x * blockDim.x + threadIdx.x;
    if (b >= BB) return;
    int len = lengths[b];
    float score = 0.0f;
    int prev = START_TAG;
    for (int t = 0; t < len; t++) {
        int nxt = tags[b * TT + t];
        score += trans[nxt * KTAG + prev] + emis[((size_t)t * BB + b) * KTAG + nxt];
        prev = nxt;
    }
    score += trans[STOP_TAG * KTAG + prev];
    out[b] = logz[b] - score;
}

extern "C" void kernel_launch(void* const* d_in, const int* in_sizes, int n_in,
                              void* d_out, int out_size, void* d_ws, size_t ws_size,
                              hipStream_t stream)
{
    (void)in_sizes; (void)n_in; (void)out_size; (void)ws_size;
    const int*   x     = (const int*)d_in[0];
    const int*   lens  = (const int*)d_in[1];
    const int*   tags  = (const int*)d_in[2];
    const float* emb   = (const float*)d_in[3];
    const float* Wihf  = (const float*)d_in[4];
    const float* Whhf  = (const float*)d_in[5];
    const float* bihf  = (const float*)d_in[6];
    const float* bhhf  = (const float*)d_in[7];
    const float* Wihb  = (const float*)d_in[8];
    const float* Whhb  = (const float*)d_in[9];
    const float* bihb  = (const float*)d_in[10];
    const float* bhhb  = (const float*)d_in[11];
    const float* fcW   = (const float*)d_in[12];
    const float* fcb   = (const float*)d_in[13];
    const float* trans = (const float*)d_in[14];
    const float* h0    = (const float*)d_in[15];
    const float* c0    = (const float*)d_in[16];
    float* out = (float*)d_out;

    char* ws = (char*)d_ws;
    size_t off = 0;
    auto alloc = [&](size_t bytes) {
        void* p = ws + off;
        off += (bytes + 255) & ~(size_t)255;
        return p;
    };
    unsigned short* xs   = (unsigned short*)alloc((size_t)TT * BB * EMBD * 2);
    unsigned short* Wr   = (unsigned short*)alloc((size_t)2 * 2048 * 768 * 2);
    float*          bias2= (float*)alloc((size_t)2 * 2048 * 4);
    unsigned short* hA   = (unsigned short*)alloc((size_t)2 * BB * HID * 2);
    unsigned short* hB   = (unsigned short*)alloc((size_t)2 * BB * HID * 2);
    float*          cbuf = (float*)alloc((size_t)2 * BB * HID * 4);
    unsigned short* hsf  = (unsigned short*)alloc((size_t)TT * BB * HID * 2);
    unsigned short* hsb  = (unsigned short*)alloc((size_t)TT * BB * HID * 2);
    float*          emis = (float*)alloc((size_t)TT * BB * KTAG * 4);
    float*          logz = (float*)alloc((size_t)BB * 4);

    prep_state<<<512, 256, 0, stream>>>(h0, c0, bihf, bhhf, bihb, bhhb, hA, cbuf, bias2);
    xs_gather<<<4096, 256, 0, stream>>>(x, emb, xs);
    w_reorder<<<1536, 256, 0, stream>>>(Wihf, Whhf, Wihb, Whhb, Wr);

    unsigned short* hb[2] = { hA, hB };
    for (int s = 0; s < TT; s++) {
        int cur = s & 1, nxt = cur ^ 1;
        lstm_step_mfma<<<256, 256, 0, stream>>>(xs, Wr, bias2, lens,
                                                hb[cur], hb[nxt], cbuf, hsf, hsb, s);
    }
    emissions_wave<<<8192, 256, 0, stream>>>(hsf, hsb, fcW, fcb, emis);
    crf_partition_kernel<<<BB, 64, 0, stream>>>(emis, lens, trans, logz);
    gold_kernel<<<1, BB, 0, stream>>>(emis, tags, lens, trans, logz, out);
}